// Round 3
// baseline (3018.383 us; speedup 1.0000x reference)
//
#include <hip/hip_runtime.h>
#include <stdint.h>

#define N_BATCH 32
#define CHN     256
#define HW      56
#define HP      58

// xpad layout (uint4 "cells" of 4 u32 = 128 channel-bits):
//   cell(n, hp, h, wp) = ((n*58 + hp)*2 + h)*58 + wp,  h = channel-half
#define XPAD_CELLS (N_BATCH * HP * 2 * HP)   // 215,296 cells
#define XPAD_U32   (XPAD_CELLS * 4)

// ---------------- fused prep (UNCHANGED from verified baseline) -------------
__global__ __launch_bounds__(256) void prep_kernel(const float* __restrict__ x,
                                                   const float* __restrict__ wsrc,
                                                   uint32_t* __restrict__ xpad,
                                                   uint32_t* __restrict__ wbits,
                                                   int* __restrict__ wpop) {
    __shared__ int part[9][4];
    int bid  = blockIdx.x;
    int t    = threadIdx.x;
    int lane = t & 63;

    if (bid < 784) {
        int tid = bid * 256 + t;          // 0..200703
        int n   = tid / 6272;             // 6272 = 3136 px * 2 halves
        int rem = tid - n * 6272;
        int hf  = rem / 3136;             // channel half
        int pq  = rem - hf * 3136;        // pixel in plane; lane-consecutive

        const float* src = x + ((size_t)(n * 256 + hf * 128)) * 3136 + pq;
        uint32_t b0 = 0, b1 = 0, b2 = 0, b3 = 0;
#pragma unroll
        for (int g = 0; g < 8; g++) {
            float v[16];
#pragma unroll
            for (int i = 0; i < 16; i++) v[i] = src[(size_t)(g * 16 + i) * 3136];
#pragma unroll
            for (int i = 0; i < 16; i++) {
                int c = g * 16 + i;       // 0..127 within half
                uint32_t b = v[i] > 0.0f ? 1u : 0u;
                if ((c >> 5) == 0) b0 |= b << (c & 31);
                else if ((c >> 5) == 1) b1 |= b << (c & 31);
                else if ((c >> 5) == 2) b2 |= b << (c & 31);
                else b3 |= b << (c & 31);
            }
        }
        int h = pq / 56;
        int w = pq - h * 56;
        uint32_t cell = ((uint32_t)(n * HP + h + 1) * 2 + hf) * HP + (w + 1);
        ((uint4*)xpad)[cell] = make_uint4(b0, b1, b2, b3);
    } else if (bid < 841) {
        int u = (bid - 784) * 256 + t;
        if (u < 14592) {
            int p = u / 228;
            int e = u - p * 228;
            int n = p >> 1, h = p & 1;
            int hp, wp;
            if (e < 58)       { hp = 0;       wp = e;       }
            else if (e < 116) { hp = 57;      wp = e - 58;  }
            else if (e < 172) { hp = e - 115; wp = 0;       }
            else              { hp = e - 171; wp = 57;      }
            uint32_t cell = ((uint32_t)(n * HP + hp) * 2 + h) * HP + wp;
            ((uint4*)xpad)[cell] = make_uint4(0u, 0u, 0u, 0u);
        }
    } else {
        int o  = bid - 841;
        int wv = t >> 6;
        const float* p = wsrc + ((size_t)o * 256 + t) * 9;
        float v[9];
#pragma unroll
        for (int tap = 0; tap < 9; tap++) v[tap] = p[tap];
#pragma unroll
        for (int tap = 0; tap < 9; tap++) {
            unsigned long long m = __ballot(v[tap] > 0.0f);
            if (lane == 0) {
                wbits[(size_t)(o * 9 + tap) * 8 + 2 * wv]     = (uint32_t)m;
                wbits[(size_t)(o * 9 + tap) * 8 + 2 * wv + 1] = (uint32_t)(m >> 32);
                part[tap][wv] = __builtin_popcountll(m);
            }
        }
        __syncthreads();
        if (t < 9) wpop[o * 9 + t] = part[t][0] + part[t][1] + part[t][2] + part[t][3];
    }
}

// ---------------- binary conv: lane = output channel ------------------------
// Round-1 compute structure (88 VGPR, no spill) + round-2's validated short
// obuf (34.8 KB LDS -> 4 blocks/CU -> 4 waves/SIMD) + barrier-free drain.
// Block = (row h, batch n), 4 waves; wave wv owns o = wv*64 + lane.
// W (72 u32) resident in VGPRs; X broadcast from a 3-row LDS strip
// (18 uniform ds_read_b128 per pixel).
__global__ __launch_bounds__(256, 4)
void conv_kernel(const uint32_t* __restrict__ xpad,
                 const uint32_t* __restrict__ wbits,
                 const int* __restrict__ wpop,
                 float* __restrict__ out) {
    __shared__ uint4 sx[3 * 2 * HP];          // 348 cells = 5,568 B
    __shared__ short obuf[4 * 64 * 57];       // 29,184 B (57 coprime w/ 32 banks)

    int t    = threadIdx.x;
    int lane = t & 63;
    int wv   = t >> 6;
    int h    = blockIdx.x;                    // output row 0..55
    int n    = blockIdx.y;

    // stage padded input rows h..h+2 (348 contiguous cells)
    const uint4* xg = (const uint4*)xpad + ((size_t)n * HP + h) * (2 * HP);
    for (int i = t; i < 3 * 2 * HP; i += 256) sx[i] = xg[i];

    // per-lane weights: o = wv*64 + lane, 72 words = 18 uint4, loaded ONCE
    int o = wv * 64 + lane;
    const uint4* wsrc4 = (const uint4*)(wbits + (size_t)o * 72);
    uint4 W4[18];
#pragma unroll
    for (int i = 0; i < 18; i++) W4[i] = wsrc4[i];

    const int* wpa = wpop + (size_t)o * 9;
    int pa[9];
#pragma unroll
    for (int i = 0; i < 9; i++) pa[i] = wpa[i];

    __syncthreads();

    short* ob  = obuf + wv * (64 * 57) + lane * 57;
    bool hedge = (h == 0) | (h == 55);

#pragma unroll 2
    for (int w = 0; w < 56; w++) {
        const uint4* cb = sx + w;             // wave-uniform base; 18 imm offsets
        int a0 = 0, a1 = 0, a2 = 0, a3 = 0;   // 4 independent popcount chains
#pragma unroll
        for (int r = 0; r < 3; r++)
#pragma unroll
            for (int dw = 0; dw < 3; dw++)
#pragma unroll
                for (int hf = 0; hf < 2; hf++) {
                    uint4 Xc = cb[(r * 2 + hf) * HP + dw];      // broadcast ds_read_b128
                    uint4 Wc = W4[(r * 3 + dw) * 2 + hf];
                    a0 += __builtin_popcount(Xc.x ^ Wc.x);
                    a1 += __builtin_popcount(Xc.y ^ Wc.y);
                    a2 += __builtin_popcount(Xc.z ^ Wc.z);
                    a3 += __builtin_popcount(Xc.w ^ Wc.w);
                }
        int va = 2304 - 2 * ((a0 + a1) + (a2 + a3));
        if (hedge | (w == 0) | (w == 55)) {   // wave-uniform branch
            int ca = 0;
#pragma unroll
            for (int dh = 0; dh < 3; dh++)
#pragma unroll
                for (int dw = 0; dw < 3; dw++)
                    if ((unsigned)(h + dh - 1) >= 56u || (unsigned)(w + dw - 1) >= 56u)
                        ca += 256 - 2 * pa[dh * 3 + dw];
            va -= ca;
        }
        ob[w] = (short)va;                    // 2 lanes/dword write: ~free (m136)
    }

    // drain: per-wave buffer, within-wave DS ops are in-order -> no barrier.
    // lane = w (coalesced 224B float row stores), loop over this wave's 64 o's
    if (lane < 56) {
        const short* obw = obuf + wv * (64 * 57);
        float* orow = out + (((size_t)n * 256 + wv * 64) * 56 + h) * 56 + lane;
#pragma unroll 8
        for (int o2 = 0; o2 < 64; o2++)
            orow[(size_t)o2 * 3136] = (float)obw[o2 * 57 + lane];
    }
}

extern "C" void kernel_launch(void* const* d_in, const int* in_sizes, int n_in,
                              void* d_out, int out_size, void* d_ws, size_t ws_size,
                              hipStream_t stream) {
    const float* x    = (const float*)d_in[0];
    const float* wsrc = (const float*)d_in[1];
    float* out = (float*)d_out;

    uint32_t* xpad  = (uint32_t*)d_ws;                    // 3.44 MB
    uint32_t* wbits = xpad + XPAD_U32;                    // 18432 u32
    int*      wpop  = (int*)(wbits + 256 * 9 * 8);        // 2304 int

    prep_kernel<<<1097, 256, 0, stream>>>(x, wsrc, xpad, wbits, wpop);
    conv_kernel<<<dim3(HW, N_BATCH), 256, 0, stream>>>(xpad, wbits, wpop, out);
}

// Round 4
// 319.293 us; speedup vs baseline: 9.4533x; 9.4533x over previous
//
#include <hip/hip_runtime.h>
#include <stdint.h>

#define N_BATCH 32
#define CHN     256
#define HW      56
#define HP      58

// xpad layout (uint4 "cells" of 4 u32 = 128 channel-bits):
//   cell(n, hp, h, wp) = ((n*58 + hp)*2 + h)*58 + wp,  h = channel-half
#define XPAD_CELLS (N_BATCH * HP * 2 * HP)   // 215,296 cells
#define XPAD_U32   (XPAD_CELLS * 4)

// ---------------- fused prep (UNCHANGED from verified baseline) -------------
__global__ __launch_bounds__(256) void prep_kernel(const float* __restrict__ x,
                                                   const float* __restrict__ wsrc,
                                                   uint32_t* __restrict__ xpad,
                                                   uint32_t* __restrict__ wbits,
                                                   int* __restrict__ wpop) {
    __shared__ int part[9][4];
    int bid  = blockIdx.x;
    int t    = threadIdx.x;
    int lane = t & 63;

    if (bid < 784) {
        int tid = bid * 256 + t;          // 0..200703
        int n   = tid / 6272;             // 6272 = 3136 px * 2 halves
        int rem = tid - n * 6272;
        int hf  = rem / 3136;             // channel half
        int pq  = rem - hf * 3136;        // pixel in plane; lane-consecutive

        const float* src = x + ((size_t)(n * 256 + hf * 128)) * 3136 + pq;
        uint32_t b0 = 0, b1 = 0, b2 = 0, b3 = 0;
#pragma unroll
        for (int g = 0; g < 8; g++) {
            float v[16];
#pragma unroll
            for (int i = 0; i < 16; i++) v[i] = src[(size_t)(g * 16 + i) * 3136];
#pragma unroll
            for (int i = 0; i < 16; i++) {
                int c = g * 16 + i;       // 0..127 within half
                uint32_t b = v[i] > 0.0f ? 1u : 0u;
                if ((c >> 5) == 0) b0 |= b << (c & 31);
                else if ((c >> 5) == 1) b1 |= b << (c & 31);
                else if ((c >> 5) == 2) b2 |= b << (c & 31);
                else b3 |= b << (c & 31);
            }
        }
        int h = pq / 56;
        int w = pq - h * 56;
        uint32_t cell = ((uint32_t)(n * HP + h + 1) * 2 + hf) * HP + (w + 1);
        ((uint4*)xpad)[cell] = make_uint4(b0, b1, b2, b3);
    } else if (bid < 841) {
        int u = (bid - 784) * 256 + t;
        if (u < 14592) {
            int p = u / 228;
            int e = u - p * 228;
            int n = p >> 1, h = p & 1;
            int hp, wp;
            if (e < 58)       { hp = 0;       wp = e;       }
            else if (e < 116) { hp = 57;      wp = e - 58;  }
            else if (e < 172) { hp = e - 115; wp = 0;       }
            else              { hp = e - 171; wp = 57;      }
            uint32_t cell = ((uint32_t)(n * HP + hp) * 2 + h) * HP + wp;
            ((uint4*)xpad)[cell] = make_uint4(0u, 0u, 0u, 0u);
        }
    } else {
        int o  = bid - 841;
        int wv = t >> 6;
        const float* p = wsrc + ((size_t)o * 256 + t) * 9;
        float v[9];
#pragma unroll
        for (int tap = 0; tap < 9; tap++) v[tap] = p[tap];
#pragma unroll
        for (int tap = 0; tap < 9; tap++) {
            unsigned long long m = __ballot(v[tap] > 0.0f);
            if (lane == 0) {
                wbits[(size_t)(o * 9 + tap) * 8 + 2 * wv]     = (uint32_t)m;
                wbits[(size_t)(o * 9 + tap) * 8 + 2 * wv + 1] = (uint32_t)(m >> 32);
                part[tap][wv] = __builtin_popcountll(m);
            }
        }
        __syncthreads();
        if (t < 9) wpop[o * 9 + t] = part[t][0] + part[t][1] + part[t][2] + part[t][3];
    }
}

// ---------------- binary conv: lane = output channel ------------------------
// Round-1 compute structure + short obuf (34.8 KB LDS). __launch_bounds__
// min-waves arg MUST stay 2: declaring 4 forces a <=128 VGPR target and the
// allocator spills W4 into the pixel loop (round 2/3: 6.9 GB FETCH, 64 VGPR,
// 2.9 ms). (256,2) = 256-VGPR ceiling; HW still reaches 4 blocks/CU via LDS.
__global__ __launch_bounds__(256, 2)
void conv_kernel(const uint32_t* __restrict__ xpad,
                 const uint32_t* __restrict__ wbits,
                 const int* __restrict__ wpop,
                 float* __restrict__ out) {
    __shared__ uint4 sx[3 * 2 * HP];          // 348 cells = 5,568 B
    __shared__ short obuf[4 * 64 * 57];       // 29,184 B (57 coprime w/ 32 banks)

    int t    = threadIdx.x;
    int lane = t & 63;
    int wv   = t >> 6;
    int h    = blockIdx.x;                    // output row 0..55
    int n    = blockIdx.y;

    // stage padded input rows h..h+2 (348 contiguous cells)
    const uint4* xg = (const uint4*)xpad + ((size_t)n * HP + h) * (2 * HP);
    for (int i = t; i < 3 * 2 * HP; i += 256) sx[i] = xg[i];

    // per-lane weights: o = wv*64 + lane, 72 words = 18 uint4, loaded ONCE
    int o = wv * 64 + lane;
    const uint4* wsrc4 = (const uint4*)(wbits + (size_t)o * 72);
    uint4 W4[18];
#pragma unroll
    for (int i = 0; i < 18; i++) W4[i] = wsrc4[i];

    const int* wpa = wpop + (size_t)o * 9;
    int pa[9];
#pragma unroll
    for (int i = 0; i < 9; i++) pa[i] = wpa[i];

    __syncthreads();

    short* ob  = obuf + wv * (64 * 57) + lane * 57;
    bool hedge = (h == 0) | (h == 55);

#pragma unroll 2
    for (int w = 0; w < 56; w++) {
        const uint4* cb = sx + w;             // wave-uniform base; 18 imm offsets
        int a0 = 0, a1 = 0, a2 = 0, a3 = 0;   // 4 independent popcount chains
#pragma unroll
        for (int r = 0; r < 3; r++)
#pragma unroll
            for (int dw = 0; dw < 3; dw++)
#pragma unroll
                for (int hf = 0; hf < 2; hf++) {
                    uint4 Xc = cb[(r * 2 + hf) * HP + dw];      // broadcast ds_read_b128
                    uint4 Wc = W4[(r * 3 + dw) * 2 + hf];
                    a0 += __builtin_popcount(Xc.x ^ Wc.x);
                    a1 += __builtin_popcount(Xc.y ^ Wc.y);
                    a2 += __builtin_popcount(Xc.z ^ Wc.z);
                    a3 += __builtin_popcount(Xc.w ^ Wc.w);
                }
        int va = 2304 - 2 * ((a0 + a1) + (a2 + a3));
        if (hedge | (w == 0) | (w == 55)) {   // wave-uniform branch
            int ca = 0;
#pragma unroll
            for (int dh = 0; dh < 3; dh++)
#pragma unroll
                for (int dw = 0; dw < 3; dw++)
                    if ((unsigned)(h + dh - 1) >= 56u || (unsigned)(w + dw - 1) >= 56u)
                        ca += 256 - 2 * pa[dh * 3 + dw];
            va -= ca;
        }
        ob[w] = (short)va;                    // 2 lanes/dword write: ~free (m136)
    }

    // drain: per-wave buffer, within-wave DS ops are in-order -> no barrier.
    // lane = w (coalesced 224B float row stores), loop over this wave's 64 o's
    if (lane < 56) {
        const short* obw = obuf + wv * (64 * 57);
        float* orow = out + (((size_t)n * 256 + wv * 64) * 56 + h) * 56 + lane;
#pragma unroll 8
        for (int o2 = 0; o2 < 64; o2++)
            orow[(size_t)o2 * 3136] = (float)obw[o2 * 57 + lane];
    }
}

extern "C" void kernel_launch(void* const* d_in, const int* in_sizes, int n_in,
                              void* d_out, int out_size, void* d_ws, size_t ws_size,
                              hipStream_t stream) {
    const float* x    = (const float*)d_in[0];
    const float* wsrc = (const float*)d_in[1];
    float* out = (float*)d_out;

    uint32_t* xpad  = (uint32_t*)d_ws;                    // 3.44 MB
    uint32_t* wbits = xpad + XPAD_U32;                    // 18432 u32
    int*      wpop  = (int*)(wbits + 256 * 9 * 8);        // 2304 int

    prep_kernel<<<1097, 256, 0, stream>>>(x, wsrc, xpad, wbits, wpop);
    conv_kernel<<<dim3(HW, N_BATCH), 256, 0, stream>>>(xpad, wbits, wpop, out);
}

// Round 5
// 307.635 us; speedup vs baseline: 9.8116x; 1.0379x over previous
//
#include <hip/hip_runtime.h>
#include <stdint.h>

#define N_BATCH 32
#define CHN     256
#define HW      56
#define HP      58

// xpad layout (uint4 "cells" of 4 u32 = 128 channel-bits):
//   cell(n, hp, h, wp) = ((n*58 + hp)*2 + h)*58 + wp,  h = channel-half
#define XPAD_CELLS (N_BATCH * HP * 2 * HP)   // 215,296 cells
#define XPAD_U32   (XPAD_CELLS * 4)

// ---------------- fused prep (UNCHANGED from verified baseline) -------------
__global__ __launch_bounds__(256) void prep_kernel(const float* __restrict__ x,
                                                   const float* __restrict__ wsrc,
                                                   uint32_t* __restrict__ xpad,
                                                   uint32_t* __restrict__ wbits,
                                                   int* __restrict__ wpop) {
    __shared__ int part[9][4];
    int bid  = blockIdx.x;
    int t    = threadIdx.x;
    int lane = t & 63;

    if (bid < 784) {
        int tid = bid * 256 + t;          // 0..200703
        int n   = tid / 6272;             // 6272 = 3136 px * 2 halves
        int rem = tid - n * 6272;
        int hf  = rem / 3136;             // channel half
        int pq  = rem - hf * 3136;        // pixel in plane; lane-consecutive

        const float* src = x + ((size_t)(n * 256 + hf * 128)) * 3136 + pq;
        uint32_t b0 = 0, b1 = 0, b2 = 0, b3 = 0;
#pragma unroll
        for (int g = 0; g < 8; g++) {
            float v[16];
#pragma unroll
            for (int i = 0; i < 16; i++) v[i] = src[(size_t)(g * 16 + i) * 3136];
#pragma unroll
            for (int i = 0; i < 16; i++) {
                int c = g * 16 + i;       // 0..127 within half
                uint32_t b = v[i] > 0.0f ? 1u : 0u;
                if ((c >> 5) == 0) b0 |= b << (c & 31);
                else if ((c >> 5) == 1) b1 |= b << (c & 31);
                else if ((c >> 5) == 2) b2 |= b << (c & 31);
                else b3 |= b << (c & 31);
            }
        }
        int h = pq / 56;
        int w = pq - h * 56;
        uint32_t cell = ((uint32_t)(n * HP + h + 1) * 2 + hf) * HP + (w + 1);
        ((uint4*)xpad)[cell] = make_uint4(b0, b1, b2, b3);
    } else if (bid < 841) {
        int u = (bid - 784) * 256 + t;
        if (u < 14592) {
            int p = u / 228;
            int e = u - p * 228;
            int n = p >> 1, h = p & 1;
            int hp, wp;
            if (e < 58)       { hp = 0;       wp = e;       }
            else if (e < 116) { hp = 57;      wp = e - 58;  }
            else if (e < 172) { hp = e - 115; wp = 0;       }
            else              { hp = e - 171; wp = 57;      }
            uint32_t cell = ((uint32_t)(n * HP + hp) * 2 + h) * HP + wp;
            ((uint4*)xpad)[cell] = make_uint4(0u, 0u, 0u, 0u);
        }
    } else {
        int o  = bid - 841;
        int wv = t >> 6;
        const float* p = wsrc + ((size_t)o * 256 + t) * 9;
        float v[9];
#pragma unroll
        for (int tap = 0; tap < 9; tap++) v[tap] = p[tap];
#pragma unroll
        for (int tap = 0; tap < 9; tap++) {
            unsigned long long m = __ballot(v[tap] > 0.0f);
            if (lane == 0) {
                wbits[(size_t)(o * 9 + tap) * 8 + 2 * wv]     = (uint32_t)m;
                wbits[(size_t)(o * 9 + tap) * 8 + 2 * wv + 1] = (uint32_t)(m >> 32);
                part[tap][wv] = __builtin_popcountll(m);
            }
        }
        __syncthreads();
        if (t < 9) wpop[o * 9 + t] = part[t][0] + part[t][1] + part[t][2] + part[t][3];
    }
}

// ---------------- binary conv: 2 output channels per lane -------------------
// DS-return-BW bound before (18 broadcast b128/px re-read by each of 4 waves,
// model 141us ~= measured 152). Now each cell read feeds TWO o's (o, o+128):
// wave wv: o-group og=wv&1 (o = og*64+lane, +128), pixel half pH=wv>>1.
// DS reads/block halve 4032->2016. Regs: WA+WB 144 + 24 cells + 8 acc +
// 9 packed-wpop ~= 205 < 256 ceiling of (256,2) -- min-waves MUST stay 2
// (4 forces <=128 target -> W spills into the px loop; rounds 2/3: 2.9 ms).
__global__ __launch_bounds__(256, 2)
void conv_kernel(const uint32_t* __restrict__ xpad,
                 const uint32_t* __restrict__ wbits,
                 const int* __restrict__ wpop,
                 float* __restrict__ out) {
    __shared__ uint4 sx[3 * 2 * HP];          // 348 cells = 5,568 B
    __shared__ short obuf[256 * 57];          // 29,184 B (57 coprime w/ 32 banks)

    int t    = threadIdx.x;
    int lane = t & 63;
    int wv   = t >> 6;
    int og   = wv & 1;                        // o-group
    int pH   = wv >> 1;                       // pixel half
    int h    = blockIdx.x;                    // output row 0..55
    int n    = blockIdx.y;

    // stage padded input rows h..h+2 (348 contiguous cells)
    const uint4* xg = (const uint4*)xpad + ((size_t)n * HP + h) * (2 * HP);
    for (int i = t; i < 3 * 2 * HP; i += 256) sx[i] = xg[i];

    // per-lane weights for o1 = og*64+lane and o2 = o1+128 (36 uint4 = 144 VGPR)
    int o1 = og * 64 + lane;
    const uint4* w1p = (const uint4*)(wbits + (size_t)o1 * 72);
    const uint4* w2p = (const uint4*)(wbits + (size_t)(o1 + 128) * 72);
    uint4 WA[18], WB[18];
#pragma unroll
    for (int i = 0; i < 18; i++) WA[i] = w1p[i];
#pragma unroll
    for (int i = 0; i < 18; i++) WB[i] = w2p[i];

    // wpop for both o's, packed two-per-u32 (values <= 256 fit 16 bits)
    const int* pp1 = wpop + (size_t)o1 * 9;
    const int* pp2 = wpop + (size_t)(o1 + 128) * 9;
    uint32_t papack[9];
#pragma unroll
    for (int i = 0; i < 9; i++)
        papack[i] = (uint32_t)pp1[i] | ((uint32_t)pp2[i] << 16);

    __syncthreads();

    short* ob1 = obuf + o1 * 57;
    short* ob2 = obuf + (o1 + 128) * 57;
    bool hedge = (h == 0) | (h == 55);
    int w0 = pH * 28;

#pragma unroll 1
    for (int wi = 0; wi < 28; wi++) {
        int w = w0 + wi;
        const uint4* cb = sx + w;             // wave-uniform base; imm offsets
        int a0 = 0, a1 = 0, a2 = 0, a3 = 0;   // o1 chains
        int b0 = 0, b1 = 0, b2 = 0, b3 = 0;   // o2 chains
#pragma unroll
        for (int dw = 0; dw < 3; dw++)
#pragma unroll
            for (int rr = 0; rr < 6; rr++) {  // rr = r*2+hf
                uint4 xc = cb[rr * HP + dw];  // ONE broadcast read, EIGHT uses
                uint4 wa = WA[((rr >> 1) * 3 + dw) * 2 + (rr & 1)];
                uint4 wb = WB[((rr >> 1) * 3 + dw) * 2 + (rr & 1)];
                a0 += __builtin_popcount(xc.x ^ wa.x);
                a1 += __builtin_popcount(xc.y ^ wa.y);
                a2 += __builtin_popcount(xc.z ^ wa.z);
                a3 += __builtin_popcount(xc.w ^ wa.w);
                b0 += __builtin_popcount(xc.x ^ wb.x);
                b1 += __builtin_popcount(xc.y ^ wb.y);
                b2 += __builtin_popcount(xc.z ^ wb.z);
                b3 += __builtin_popcount(xc.w ^ wb.w);
            }
        int va = 2304 - 2 * ((a0 + a1) + (a2 + a3));
        int vb = 2304 - 2 * ((b0 + b1) + (b2 + b3));
        if (hedge | (w == 0) | (w == 55)) {   // wave-uniform branch
            int ca = 0, cc = 0;
#pragma unroll
            for (int dh = 0; dh < 3; dh++)
#pragma unroll
                for (int dw = 0; dw < 3; dw++)
                    if ((unsigned)(h + dh - 1) >= 56u || (unsigned)(w + dw - 1) >= 56u) {
                        uint32_t pk = papack[dh * 3 + dw];
                        ca += 256 - 2 * (int)(pk & 0xffffu);
                        cc += 256 - 2 * (int)(pk >> 16);
                    }
            va -= ca;
            vb -= cc;
        }
        ob1[w] = (short)va;
        ob2[w] = (short)vb;
    }

    __syncthreads();                          // obuf rows cross pixel-half waves

    // drain: wave wv drains o in [wv*64, wv*64+64); lane = w (coalesced rows)
    if (lane < 56) {
        const short* obw = obuf + (wv * 64) * 57;
        float* orow = out + (((size_t)n * 256 + wv * 64) * 56 + h) * 56 + lane;
#pragma unroll 8
        for (int o2 = 0; o2 < 64; o2++)
            orow[(size_t)o2 * 3136] = (float)obw[o2 * 57 + lane];
    }
}

extern "C" void kernel_launch(void* const* d_in, const int* in_sizes, int n_in,
                              void* d_out, int out_size, void* d_ws, size_t ws_size,
                              hipStream_t stream) {
    const float* x    = (const float*)d_in[0];
    const float* wsrc = (const float*)d_in[1];
    float* out = (float*)d_out;

    uint32_t* xpad  = (uint32_t*)d_ws;                    // 3.44 MB
    uint32_t* wbits = xpad + XPAD_U32;                    // 18432 u32
    int*      wpop  = (int*)(wbits + 256 * 9 * 8);        // 2304 int

    prep_kernel<<<1097, 256, 0, stream>>>(x, wsrc, xpad, wbits, wpop);
    conv_kernel<<<dim3(HW, N_BATCH), 256, 0, stream>>>(xpad, wbits, wpop, out);
}